// Round 4
// baseline (26687.549 us; speedup 1.0000x reference)
//
#include <hip/hip_runtime.h>
#include <math.h>

#define Hh   512
#define TH   1536
#define LINN 128
#define RD   16          /* ring depth */
typedef unsigned long long ull;
typedef unsigned int u32;

#define WS_A     0
#define WS_CC    6144
#define WS_RING0 16384
#define WS_RING1 (16384 + Hh * RD * 8)
// ws usage ends at 16384 + 2*Hh*RD*8 = 147456 bytes

__device__ __forceinline__ float sigm(float v) { return 1.f / (1.f + __expf(-v)); }
__device__ __forceinline__ float tanh_fast(float x) { return 2.f / (1.f + __expf(-2.f * x)) - 1.f; }
__device__ __forceinline__ ull  pk(float v, u32 tag) { return ((ull)tag << 32) | (ull)__float_as_uint(v); }
__device__ __forceinline__ ull  ring_ld(const ull* p) {
    return __hip_atomic_load(p, __ATOMIC_RELAXED, __HIP_MEMORY_SCOPE_AGENT);
}
__device__ __forceinline__ void ring_st(ull* p, ull v) {
    __hip_atomic_store(p, v, __ATOMIC_RELAXED, __HIP_MEMORY_SCOPE_AGENT);
}

// ---------------------------------------------------------------- prep:
// A[row] = W_ih0[row,:]@W_proc ; CC[row] = W_ih0[row,:]@b_proc + b_ih0 (+ b_hh0 for r,z rows)
__global__ void prep(const float* __restrict__ Wih0, const float* __restrict__ Wproc,
                     const float* __restrict__ bproc, const float* __restrict__ bih0,
                     const float* __restrict__ bhh0, float* __restrict__ A,
                     float* __restrict__ CC)
{
    int row = blockIdx.x * 256 + threadIdx.x;
    if (row >= TH) return;
    const float* w = Wih0 + (size_t)row * LINN;
    float a = 0.f, c = 0.f;
    for (int k = 0; k < LINN; ++k) { float wv = w[k]; a = fmaf(wv, Wproc[k], a); c = fmaf(wv, bproc[k], c); }
    c += bih0[row];
    if (row < 2 * Hh) c += bhh0[row];
    A[row] = a; CC[row] = c;
}

// ---------------------------------------------------------------- ring init (tags + initial state, every call)
__global__ void ringinit(const float* __restrict__ mem, ull* __restrict__ ring0,
                         ull* __restrict__ ring1)
{
    const int t = threadIdx.x;          // 512 threads
    for (int slot = 0; slot < RD; ++slot) {
        ring0[slot * Hh + t] = pk(slot == RD - 1 ? mem[t]      : 0.f, 0u);
        ring1[slot * Hh + t] = pk(slot == RD - 1 ? mem[Hh + t] : 0.f, 0u);
    }
}

// ---------------------------------------------------------------- fused self-timed dataflow scan
// WG 0..63   : layer 0  (8 h-indices each; 24 rows of Whh0 in LDS)
// WG 64..191 : layer 1, 1-step lag (4 h-indices each; 24 row-equivalents of Wih1+Whh1 in LDS)
// Exchange: RD-deep rings of (float value | u32 tag) packed 8B words, relaxed agent atomics.
// All poll loads of one step issue CONCURRENTLY (single vmcnt wait -> 1 LLC RTT).
__launch_bounds__(256, 1)
__global__ void fused(const float* __restrict__ input, const float* __restrict__ resid,
                      const float* __restrict__ Whh0, const float* __restrict__ bhh0,
                      const float* __restrict__ A, const float* __restrict__ CC,
                      const float* __restrict__ Wih1, const float* __restrict__ Whh1,
                      const float* __restrict__ bih1, const float* __restrict__ bhh1,
                      ull* __restrict__ ring0, ull* __restrict__ ring1,
                      float* __restrict__ outp, int T)
{
    __shared__ __align__(16) float smem[14336];   // 56 KB
    const int tid = threadIdx.x;
    const int wg  = blockIdx.x;

    if (wg < 64) {
        // ---------------- layer 0 ----------------
        float* Wl = smem;                  // [24][512]
        float* hl = smem + 12288;          // [2][512] double buffer
        const int jl = tid >> 5;           // 0..7
        const int s2 = tid & 31;
        const int jg = wg * 8 + jl;
        for (int i = tid; i < 24 * Hh; i += 256) {
            int lr = i >> 9, k = i & (Hh - 1);
            int g = lr % 3, j = lr / 3;
            Wl[i] = Whh0[(size_t)(g * Hh + wg * 8 + j) * Hh + k];
        }
        const float Ar = A[jg], Az = A[jg + Hh], An = A[jg + 2 * Hh];
        const float Cr = CC[jg], Cz = CC[jg + Hh], Cn = CC[jg + 2 * Hh];
        const float Bn = bhh0[jg + 2 * Hh];
        const float* Wr = &Wl[(jl * 3 + 0) * Hh];
        const float* Wz = &Wl[(jl * 3 + 1) * Hh];
        const float* Wn = &Wl[(jl * 3 + 2) * Hh];
        __syncthreads();

        for (int s = 0; s < T; ++s) {
            const ull* base = ring0 + (size_t)((s - 1) & (RD - 1)) * Hh;
            const u32 tgt = (u32)s;
            ull w0 = ring_ld(base + tid);            // both loads in flight together
            ull w1 = ring_ld(base + tid + 256);
            while (((u32)(w0 >> 32) < tgt) | ((u32)(w1 >> 32) < tgt)) {
                __builtin_amdgcn_s_sleep(1);
                w0 = ring_ld(base + tid);
                w1 = ring_ld(base + tid + 256);
            }
            if (tid == 0 && s >= 8 && (s & 7) == 0) {   // amortized back-pressure:
                // require layer-1 done with step s-8 => ring0 slots safe for 8 more steps
                const ull* bp = ring1 + (size_t)((s - 8) & (RD - 1)) * Hh;
                while ((u32)(ring_ld(bp) >> 32) < (u32)(s - 7)) __builtin_amdgcn_s_sleep(1);
            }
            float* hb = hl + (s & 1) * Hh;
            hb[tid]       = __uint_as_float((u32)w0);
            hb[tid + 256] = __uint_as_float((u32)w1);
            __syncthreads();               // single barrier: double-buffered broadcast
            const float x = input[s];
            float ar = 0.f, az = 0.f, an = 0.f;
#pragma unroll
            for (int i = 0; i < 16; ++i) {
                int k = s2 + 32 * i;
                float hk = hb[k];
                ar = fmaf(Wr[k], hk, ar); az = fmaf(Wz[k], hk, az); an = fmaf(Wn[k], hk, an);
            }
#pragma unroll
            for (int o = 16; o > 0; o >>= 1) {
                ar += __shfl_xor(ar, o); az += __shfl_xor(az, o); an += __shfl_xor(an, o);
            }
            if (s2 == 0) {
                float r  = sigm(fmaf(Ar, x, Cr) + ar);
                float z  = sigm(fmaf(Az, x, Cz) + az);
                float n  = tanh_fast(fmaf(An, x, Cn) + r * (an + Bn));
                float hn = (1.f - z) * n + z * hb[jg];
                ring_st(ring0 + (size_t)(s & (RD - 1)) * Hh + jg, pk(hn, (u32)(s + 1)));
                if (s == T - 1) outp[Hh + jg] = hn;
            }
        }
    } else {
        // ---------------- layer 1 (lag 1) ----------------
        float* Wl  = smem;                 // [24][512]: per h: ihR,ihZ,ihN,hhR,hhZ,hhN
        float* hl0 = smem + 12288;         // [2][512]
        float* hl1 = smem + 13312;         // [2][512]
        const int w  = tid >> 6;           // wave 0..3
        const int l  = tid & 63;
        const int jg = (wg - 64) * 4 + w;
        for (int i = tid; i < 24 * Hh; i += 256) {
            int lr = i >> 9, k = i & (Hh - 1);
            int ww = lr / 6, q = lr % 6;
            int hj = (wg - 64) * 4 + ww;
            const float* src = (q < 3) ? &Wih1[(size_t)(q * Hh + hj) * Hh]
                                       : &Whh1[(size_t)((q - 3) * Hh + hj) * Hh];
            Wl[i] = src[k];
        }
        const float Br = bih1[jg] + bhh1[jg];
        const float Bz = bih1[jg + Hh] + bhh1[jg + Hh];
        const float Bin = bih1[jg + 2 * Hh];
        const float Bhn = bhh1[jg + 2 * Hh];
        const float* Xr = &Wl[(w * 6 + 0) * Hh];
        const float* Xz = &Wl[(w * 6 + 1) * Hh];
        const float* Xn = &Wl[(w * 6 + 2) * Hh];
        const float* Hr = &Wl[(w * 6 + 3) * Hh];
        const float* Hz = &Wl[(w * 6 + 4) * Hh];
        const float* Hn = &Wl[(w * 6 + 5) * Hh];
        float resl = resid[jg];            // live in lane 0
        __syncthreads();

        for (int u = 0; u < T; ++u) {
            const ull* b0 = ring0 + (size_t)(u & (RD - 1)) * Hh;        // h0[u], tag u+1
            const ull* b1 = ring1 + (size_t)((u - 1) & (RD - 1)) * Hh;  // h1[u-1], tag u
            const u32 t0g = (u32)(u + 1), t1g = (u32)u;
            ull a0 = ring_ld(b0 + tid);            // all four loads in flight together
            ull a1 = ring_ld(b0 + tid + 256);
            ull c0 = ring_ld(b1 + tid);
            ull c1 = ring_ld(b1 + tid + 256);
            while (((u32)(a0 >> 32) < t0g) | ((u32)(a1 >> 32) < t0g) |
                   ((u32)(c0 >> 32) < t1g) | ((u32)(c1 >> 32) < t1g)) {
                __builtin_amdgcn_s_sleep(1);
                a0 = ring_ld(b0 + tid);
                a1 = ring_ld(b0 + tid + 256);
                c0 = ring_ld(b1 + tid);
                c1 = ring_ld(b1 + tid + 256);
            }
            float* hb0 = hl0 + (u & 1) * Hh;
            float* hb1 = hl1 + (u & 1) * Hh;
            hb0[tid]       = __uint_as_float((u32)a0);
            hb0[tid + 256] = __uint_as_float((u32)a1);
            hb1[tid]       = __uint_as_float((u32)c0);
            hb1[tid + 256] = __uint_as_float((u32)c1);
            __syncthreads();               // single barrier: double-buffered broadcast
            float xr = 0.f, xz = 0.f, xn = 0.f, hr = 0.f, hz = 0.f, hq = 0.f;
#pragma unroll
            for (int i = 0; i < 8; ++i) {
                int k = l + 64 * i;
                float h0k = hb0[k], h1k = hb1[k];
                xr = fmaf(Xr[k], h0k, xr); xz = fmaf(Xz[k], h0k, xz); xn = fmaf(Xn[k], h0k, xn);
                hr = fmaf(Hr[k], h1k, hr); hz = fmaf(Hz[k], h1k, hz); hq = fmaf(Hn[k], h1k, hq);
            }
#pragma unroll
            for (int o = 32; o > 0; o >>= 1) {
                xr += __shfl_xor(xr, o); xz += __shfl_xor(xz, o); xn += __shfl_xor(xn, o);
                hr += __shfl_xor(hr, o); hz += __shfl_xor(hz, o); hq += __shfl_xor(hq, o);
            }
            if (l == 0) {
                float r   = sigm(xr + hr + Br);
                float z   = sigm(xz + hz + Bz);
                float n   = tanh_fast(xn + Bin + r * (hq + Bhn));
                float h1n = (1.f - z) * n + z * hb1[jg];
                ring_st(ring1 + (size_t)(u & (RD - 1)) * Hh + jg, pk(h1n, (u32)(u + 1)));
                resl = sigm(resl + h1n);
                if (u == T - 1) { outp[jg] = resl; outp[2 * Hh + jg] = h1n; }
            }
        }
    }
}

// ---------------------------------------------------------------- host
extern "C" void kernel_launch(void* const* d_in, const int* in_sizes, int n_in,
                              void* d_out, int out_size, void* d_ws, size_t ws_size,
                              hipStream_t stream)
{
    const float* input    = (const float*)d_in[0];
    const float* residual = (const float*)d_in[1];
    const float* memory   = (const float*)d_in[2];
    const float* Wproc    = (const float*)d_in[3];
    const float* bproc    = (const float*)d_in[4];
    const float* Wih0     = (const float*)d_in[5];
    const float* Whh0     = (const float*)d_in[6];
    const float* bih0     = (const float*)d_in[7];
    const float* bhh0     = (const float*)d_in[8];
    const float* Wih1     = (const float*)d_in[9];
    const float* Whh1     = (const float*)d_in[10];
    const float* bih1     = (const float*)d_in[11];
    const float* bhh1     = (const float*)d_in[12];
    const int L = in_sizes[0];
    const int T = L - 1;
    float* out = (float*)d_out;
    char* ws = (char*)d_ws;

    float* A     = (float*)(ws + WS_A);
    float* CC    = (float*)(ws + WS_CC);
    ull*   ring0 = (ull*)(ws + WS_RING0);
    ull*   ring1 = (ull*)(ws + WS_RING1);

    prep<<<dim3((TH + 255) / 256), dim3(256), 0, stream>>>(Wih0, Wproc, bproc, bih0, bhh0, A, CC);
    ringinit<<<dim3(1), dim3(512), 0, stream>>>(memory, ring0, ring1);
    fused<<<dim3(192), dim3(256), 0, stream>>>(input, residual, Whh0, bhh0, A, CC,
                                               Wih1, Whh1, bih1, bhh1,
                                               ring0, ring1, out, T);
}